// Round 4
// baseline (396.759 us; speedup 1.0000x reference)
//
#include <hip/hip_runtime.h>

#define EPB 16          // envs per block
#define BLOCK 192       // 12 threads per env * 16 envs = 3 waves
#define HS 292          // H LDS stride (288 + 4 pad, 16B-aligned, bank-spread)
#define GS 148          // Ginv LDS stride (144 + 4 pad, 16B-aligned)
#define SS 28           // s / aux stride (24 + 4 pad, 16B-aligned)

// Gauss-Jordan, 12 rows, thread t (0..11) owns exactly row t. Width W.
// Pivot row broadcast via LDS. SPD input -> no pivoting.
template<int W>
__device__ __forceinline__ void gj12(float* r, float* piv, int t) {
#pragma unroll
  for (int k = 0; k < 12; ++k) {
    if (t == k) {
      float inv = 1.0f / r[k];
#pragma unroll
      for (int c = 0; c < W; ++c) { r[c] *= inv; piv[c] = r[c]; }
    }
    __syncthreads();
    float m = (t == k) ? 0.0f : r[k];
#pragma unroll
    for (int c = 0; c < W; ++c) r[c] = fmaf(-m, piv[c], r[c]);
    __syncthreads();
  }
}

// 12 threads/env, 2 rows (2t, 2t+1) per thread: Fm is 48 floats/thread so the
// whole loop live-set (~80) fits even a 128-VGPR cap with slack -> no scratch.
__global__ __launch_bounds__(BLOCK, 2)
void pdhg_kernel(const float* __restrict__ P, const float* __restrict__ q,
                 const float* __restrict__ H, const float* __restrict__ b,
                 const float* __restrict__ cf, const int* __restrict__ itp,
                 float* __restrict__ out, int Btot) {
  __shared__ __align__(16) float sH[EPB * HS];
  __shared__ __align__(16) float sGi[EPB * GS];   // P, then Ginv
  __shared__ __align__(16) float sS[EPB * SS];    // s vector (single buffer)
  __shared__ __align__(16) float sAux[EPB * SS];  // piv / tsol / v / masks / z-b

  const int tid = threadIdx.x;
  const int e   = tid / 12;
  const int t   = tid - e * 12;
  const int env = blockIdx.x * EPB + e;
  const int niter = itp[0];
  const int r0 = 2 * t, r1 = 2 * t + 1;

  // ---- coalesced float4 staging of H and P into LDS ----
  {
    const float4* gH = (const float4*)(H + (size_t)blockIdx.x * EPB * 288);
#pragma unroll
    for (int rep = 0; rep < 6; ++rep) {          // EPB*72 / BLOCK = 6
      int i = tid + rep * BLOCK;
      int ee = i / 72, off = i - ee * 72;
      *(float4*)&sH[ee * HS + off * 4] = gH[i];
    }
    const float4* gP = (const float4*)(P + (size_t)blockIdx.x * EPB * 144);
#pragma unroll
    for (int rep = 0; rep < 3; ++rep) {          // EPB*36 / BLOCK = 3
      int i = tid + rep * BLOCK;
      int ee = i / 36, off = i - ee * 36;
      *(float4*)&sGi[ee * GS + off * 4] = gP[i];
    }
  }
  __syncthreads();

  const float* myH = &sH[e * HS];
  float* piv = &sAux[e * SS];

  // ---- build [G|I] row t (G = P + HtH) and [P|q] row t ----
  float g[24], p[13];
  {
    float hc[24];
#pragma unroll
    for (int k = 0; k < 24; ++k) hc[k] = myH[k * 12 + t];   // column t of H
#pragma unroll
    for (int c = 0; c < 12; ++c) {
      float acc = sGi[e * GS + t * 12 + c];
#pragma unroll
      for (int k = 0; k < 24; ++k) acc = fmaf(hc[k], myH[k * 12 + c], acc);
      g[c] = acc;
    }
#pragma unroll
    for (int c = 0; c < 12; ++c) g[12 + c] = (c == t) ? 1.0f : 0.0f;
#pragma unroll
    for (int c = 0; c < 12; ++c) p[c] = sGi[e * GS + t * 12 + c];
    p[12] = q[(size_t)env * 12 + t];
  }
  __syncthreads();

  // ---- invert G; write Ginv over P (p[] holds private P-row copy) ----
  gj12<24>(g, piv, t);
#pragma unroll
  for (int c = 0; c < 12; ++c) sGi[e * GS + t * 12 + c] = g[12 + c];

  // ---- solve P tsol = q (gj's first internal barrier publishes Ginv) ----
  gj12<13>(p, piv, t);
  sAux[e * SS + t] = p[12];
  __syncthreads();                 // tsol visible

  const float2 b2  = *(const float2*)&b[(size_t)env * 24 + r0];
  const float2 cf2 = *(const float2*)&cf[(size_t)env * 24 + r0];

  // ---- Fm rows r0, r1 (48 regs) + vown = H*tsol - b ----
  float Fm[2][24];
  float vown[2];
#pragma unroll
  for (int i = 0; i < 2; ++i) {
    const int r = 2 * t + i;
    float hrow[12];
#pragma unroll
    for (int c = 0; c < 12; ++c) hrow[c] = myH[r * 12 + c];
    float hg[12];
#pragma unroll
    for (int j = 0; j < 12; ++j) {
      float a = 0.f;
#pragma unroll
      for (int c = 0; c < 12; ++c) a = fmaf(hrow[c], sGi[e * GS + c * 12 + j], a);
      hg[j] = a;
    }
#pragma unroll
    for (int j = 0; j < 24; ++j) {
      float a = 0.f;
#pragma unroll
      for (int c = 0; c < 12; ++c) a = fmaf(hg[c], myH[j * 12 + c], a);
      Fm[i][j] = ((j == r) ? 1.f : 0.f) - a;
    }
    float a = 0.f;
#pragma unroll
    for (int c = 0; c < 12; ++c) a = fmaf(hrow[c], sAux[e * SS + c], a);
    vown[i] = a - ((i == 0) ? b2.x : b2.y);
  }
  __syncthreads();                 // tsol reads done
  *(float2*)&sAux[e * SS + r0] = make_float2(vown[0], vown[1]);
  __syncthreads();                 // v visible
  float mu0 = 0.f, mu1 = 0.f;
  {
    const float4* av = (const float4*)&sAux[e * SS];
#pragma unroll
    for (int jj = 0; jj < 6; ++jj) {
      float4 vj = av[jj];
      mu0 = fmaf(Fm[0][4 * jj + 0], vj.x, mu0); mu1 = fmaf(Fm[1][4 * jj + 0], vj.x, mu1);
      mu0 = fmaf(Fm[0][4 * jj + 1], vj.y, mu0); mu1 = fmaf(Fm[1][4 * jj + 1], vj.y, mu1);
      mu0 = fmaf(Fm[0][4 * jj + 2], vj.z, mu0); mu1 = fmaf(Fm[1][4 * jj + 2], vj.z, mu1);
      mu0 = fmaf(Fm[0][4 * jj + 3], vj.w, mu0); mu1 = fmaf(Fm[1][4 * jj + 3], vj.w, mu1);
    }
  }

  // ---- projection roles (fixed per thread) ----
  const int  c0   = r0 / 3, c1 = r1 / 3;        // cone index of each owned row
  const bool cone = (t < 6);                    // rows 0..11 are cone rows
  const bool mw0  = cone && (r0 % 3 == 2);      // owns a cone z-component
  const bool mw1  = cone && (r1 % 3 == 2);
  float* sEnv = &sS[e * SS];
  float* mk   = &sAux[e * SS];                  // mask slots 0..3 (reuse aux)

  // ---- iterations: s = l+z; w = Fm s + mu; l = w; z = proj(s-2w)*cf ----
  float l0 = 0.f, l1 = 0.f, z0 = 0.f, z1 = 0.f;
  for (int it = 0; it < niter; ++it) {
    float s0 = l0 + z0, s1 = l1 + z1;
    *(float2*)&sEnv[r0] = make_float2(s0, s1);
    __syncthreads();                            // barrier 1: s published
    float w0 = mu0, w1 = mu1;
    {
      const float4* sv4 = (const float4*)sEnv;
#pragma unroll
      for (int jj = 0; jj < 6; ++jj) {          // broadcast reads, conflict-free
        float4 sj = sv4[jj];
        w0 = fmaf(Fm[0][4 * jj + 0], sj.x, w0); w1 = fmaf(Fm[1][4 * jj + 0], sj.x, w1);
        w0 = fmaf(Fm[0][4 * jj + 1], sj.y, w0); w1 = fmaf(Fm[1][4 * jj + 1], sj.y, w1);
        w0 = fmaf(Fm[0][4 * jj + 2], sj.z, w0); w1 = fmaf(Fm[1][4 * jj + 2], sj.z, w1);
        w0 = fmaf(Fm[0][4 * jj + 3], sj.w, w0); w1 = fmaf(Fm[1][4 * jj + 3], sj.w, w1);
      }
    }
    float zp0 = fmaf(-2.0f, w0, s0);
    float zp1 = fmaf(-2.0f, w1, s1);
    if (mw0) mk[c0] = (zp0 > 0.0f) ? 1.0f : 0.0f;
    if (mw1) mk[c1] = (zp1 > 0.0f) ? 1.0f : 0.0f;
    __syncthreads();                            // barrier 2: masks published
    l0 = w0; l1 = w1;
    if (cone) {
      z0 = zp0 * mk[c0] * cf2.x;
      z1 = zp1 * mk[c1] * cf2.y;
    } else {
      z0 = fminf(fmaxf(zp0, -10.0f), 10.0f) * cf2.x;
      z1 = fminf(fmaxf(zp1, -10.0f), 10.0f) * cf2.y;
    }
    // single s-buffer is safe: barrier2 separates this iter's s reads from
    // the next iter's s write; mask rewrite is gated by next barrier1.
  }

  // ---- outputs: lz, then x = (HtH)^-1 Ht (z - b) ----
  float* xout  = out;
  float* lzout = out + (size_t)Btot * 12;
  *(float2*)&lzout[(size_t)env * 48 + r0]      = make_float2(l0, l1);
  *(float2*)&lzout[(size_t)env * 48 + 24 + r0] = make_float2(z0, z1);

  __syncthreads();                 // mask reads done before sAux reuse
  *(float2*)&sAux[e * SS + r0] = make_float2(z0 - b2.x, z1 - b2.y);
  __syncthreads();                 // z-b visible

  float hp[13];
  {
    float hc[24];
#pragma unroll
    for (int k = 0; k < 24; ++k) hc[k] = myH[k * 12 + t];
#pragma unroll
    for (int c = 0; c < 12; ++c) {
      float a = 0.f;
#pragma unroll
      for (int k = 0; k < 24; ++k) a = fmaf(hc[k], myH[k * 12 + c], a);
      hp[c] = a;
    }
    float a = 0.f;
#pragma unroll
    for (int k = 0; k < 24; ++k) a = fmaf(hc[k], sAux[e * SS + k], a);
    hp[12] = a;
  }
  __syncthreads();                 // rhs reads done before gj reuses sAux(piv)
  gj12<13>(hp, piv, t);
  xout[(size_t)env * 12 + t] = hp[12];
}

extern "C" void kernel_launch(void* const* d_in, const int* in_sizes, int n_in,
                              void* d_out, int out_size, void* d_ws, size_t ws_size,
                              hipStream_t stream) {
  const float* P  = (const float*)d_in[0];
  const float* q  = (const float*)d_in[1];
  const float* H  = (const float*)d_in[2];
  const float* b  = (const float*)d_in[3];
  const float* cf = (const float*)d_in[4];
  const int*   it = (const int*)d_in[5];
  float* out = (float*)d_out;
  const int B = in_sizes[1] / 12;       // q is [B,12]
  const int grid = B / EPB;             // 16384/16 = 1024 blocks, 4 blocks/CU
  pdhg_kernel<<<grid, BLOCK, 0, stream>>>(P, q, H, b, cf, it, out, B);
}

// Round 5
// 234.068 us; speedup vs baseline: 1.6951x; 1.6951x over previous
//
#include <hip/hip_runtime.h>

#define EPB 32          // envs per block
#define BLOCK 256       // 8 threads/env * 32 envs
#define HS 292          // H LDS stride (288 + 4 pad)
#define GS 148          // Ginv LDS stride (144 + 4 pad)
#define SS 28           // s / aux stride (24 + 4 pad, 16B-aligned)

// acc += dot(f4, s4)
#define FMA4(acc, f, s)                                         \
  acc = fmaf((f).x, (s).x,                                      \
        fmaf((f).y, (s).y,                                      \
        fmaf((f).z, (s).z,                                      \
        fmaf((f).w, (s).w, (acc)))))

// acc4 += s * v4 (scalar * float4)
#define VFMA(acc, s, v)                                         \
  { (acc).x = fmaf((s), (v).x, (acc).x);                        \
    (acc).y = fmaf((s), (v).y, (acc).y);                        \
    (acc).z = fmaf((s), (v).z, (acc).z);                        \
    (acc).w = fmaf((s), (v).w, (acc).w); }

struct Row6 {            // one Fm row as 6 named float4 chunks + vown
  float4 c0, c1, c2, c3, c4, c5;
  float v;
};

__device__ __forceinline__ float dot12(float4 a0, float4 a1, float4 a2,
                                       const float* __restrict__ p) {
  const float4* p4 = (const float4*)p;
  float4 b0 = p4[0], b1 = p4[1], b2 = p4[2];
  float acc = 0.f;
  FMA4(acc, a0, b0); FMA4(acc, a1, b1); FMA4(acc, a2, b2);
  return acc;
}

// Fm row r = e_r - (H[r,:] * Ginv) * H^T ; also v = H[r,:]*tsol (tsol at aux).
__device__ __forceinline__ Row6 build_row(const float* __restrict__ myH,
                                          const float* __restrict__ gi,
                                          const float* __restrict__ aux, int r) {
  const float4* hr4 = (const float4*)(myH + r * 12);
  float4 h0 = hr4[0], h1 = hr4[1], h2 = hr4[2];
  float4 gA = {0,0,0,0}, gB = {0,0,0,0}, gC = {0,0,0,0};   // hg = hrow * Ginv
#define ACC_G(c, coef)                                          \
  { const float4* g4 = (const float4*)(gi + (c) * 12);          \
    float4 r0 = g4[0], r1 = g4[1], r2 = g4[2];                  \
    VFMA(gA, coef, r0); VFMA(gB, coef, r1); VFMA(gC, coef, r2); }
  ACC_G(0, h0.x) ACC_G(1, h0.y) ACC_G(2,  h0.z) ACC_G(3,  h0.w)
  ACC_G(4, h1.x) ACC_G(5, h1.y) ACC_G(6,  h1.z) ACC_G(7,  h1.w)
  ACC_G(8, h2.x) ACC_G(9, h2.y) ACC_G(10, h2.z) ACC_G(11, h2.w)
#undef ACC_G
  Row6 R;
#define FEL(j) ((((j) == r) ? 1.0f : 0.0f) - dot12(gA, gB, gC, myH + (j) * 12))
  R.c0 = make_float4(FEL(0),  FEL(1),  FEL(2),  FEL(3));
  R.c1 = make_float4(FEL(4),  FEL(5),  FEL(6),  FEL(7));
  R.c2 = make_float4(FEL(8),  FEL(9),  FEL(10), FEL(11));
  R.c3 = make_float4(FEL(12), FEL(13), FEL(14), FEL(15));
  R.c4 = make_float4(FEL(16), FEL(17), FEL(18), FEL(19));
  R.c5 = make_float4(FEL(20), FEL(21), FEL(22), FEL(23));
#undef FEL
  R.v = dot12(h0, h1, h2, aux);     // H[r,:] * tsol
  return R;
}

// Gauss-Jordan (setup-only; register arrays here are one-time cost even if
// the compiler keeps them in scratch). Thread t owns row t; t<4 also t+8.
template<int W>
__device__ __forceinline__ void gauss_jordan(float* r0, float* r1, float* piv, int t) {
#pragma unroll
  for (int k = 0; k < 12; ++k) {
    if (k < 8) {
      if (t == k) {
        float inv = 1.0f / r0[k];
#pragma unroll
        for (int c = 0; c < W; ++c) { r0[c] *= inv; piv[c] = r0[c]; }
      }
    } else {
      if (t == k - 8) {
        float inv = 1.0f / r1[k];
#pragma unroll
        for (int c = 0; c < W; ++c) { r1[c] *= inv; piv[c] = r1[c]; }
      }
    }
    __syncthreads();
    float m0 = (t == k) ? 0.0f : r0[k];
#pragma unroll
    for (int c = 0; c < W; ++c) r0[c] = fmaf(-m0, piv[c], r0[c]);
    float m1 = ((t + 8) == k) ? 0.0f : r1[k];
#pragma unroll
    for (int c = 0; c < W; ++c) r1[c] = fmaf(-m1, piv[c], r1[c]);
    __syncthreads();
  }
}

__global__ __launch_bounds__(BLOCK, 2)
void pdhg_kernel(const float* __restrict__ P, const float* __restrict__ q,
                 const float* __restrict__ H, const float* __restrict__ b,
                 const float* __restrict__ cf, const int* __restrict__ itp,
                 float* __restrict__ out, int Btot) {
  __shared__ __align__(16) float sH[EPB * HS];
  __shared__ __align__(16) float sGi[EPB * GS];   // P, then Ginv
  __shared__ __align__(16) float sS[2 * EPB * SS];
  __shared__ __align__(16) float sAux[EPB * SS];

  const int tid = threadIdx.x;
  const int e   = tid >> 3;
  const int t   = tid & 7;
  const int env = blockIdx.x * EPB + e;
  const int niter = itp[0];
  const int r0w = 3 * t;

  // ---- coalesced float4 staging ----
  {
    const float4* gH = (const float4*)(H + (size_t)blockIdx.x * EPB * 288);
    for (int i = tid; i < EPB * 72; i += BLOCK) {
      int ee = i / 72, off = i - ee * 72;
      *(float4*)&sH[ee * HS + off * 4] = gH[i];
    }
    const float4* gP = (const float4*)(P + (size_t)blockIdx.x * EPB * 144);
    for (int i = tid; i < EPB * 36; i += BLOCK) {
      int ee = i / 36, off = i - ee * 36;
      *(float4*)&sGi[ee * GS + off * 4] = gP[i];
    }
  }
  __syncthreads();

  const float* myH = &sH[e * HS];
  const float* giB = &sGi[e * GS];
  float* piv = &sAux[e * SS];
  float* auxB = &sAux[e * SS];

  // ---- build [G|I] and [P|q] rows; GJ (setup-only arrays) ----
  float g0[24], g1[24], p0[13], p1[13];
  {
    {
      float hr[24];
#pragma unroll
      for (int k = 0; k < 24; ++k) hr[k] = myH[k * 12 + t];
#pragma unroll
      for (int c = 0; c < 12; ++c) {
        float acc = giB[t * 12 + c];
#pragma unroll
        for (int k = 0; k < 24; ++k) acc = fmaf(hr[k], myH[k * 12 + c], acc);
        g0[c] = acc;
      }
    }
#pragma unroll
    for (int c = 0; c < 12; ++c) g0[12 + c] = (c == t) ? 1.0f : 0.0f;
#pragma unroll
    for (int c = 0; c < 12; ++c) p0[c] = giB[t * 12 + c];
    p0[12] = q[(size_t)env * 12 + t];

    if (t < 4) {
      float hr2[24];
#pragma unroll
      for (int k = 0; k < 24; ++k) hr2[k] = myH[k * 12 + t + 8];
#pragma unroll
      for (int c = 0; c < 12; ++c) {
        float acc = giB[(t + 8) * 12 + c];
#pragma unroll
        for (int k = 0; k < 24; ++k) acc = fmaf(hr2[k], myH[k * 12 + c], acc);
        g1[c] = acc;
      }
#pragma unroll
      for (int c = 0; c < 12; ++c) g1[12 + c] = (c == t + 8) ? 1.0f : 0.0f;
#pragma unroll
      for (int c = 0; c < 12; ++c) p1[c] = giB[(t + 8) * 12 + c];
      p1[12] = q[(size_t)env * 12 + t + 8];
    } else {
#pragma unroll
      for (int c = 0; c < 24; ++c) g1[c] = 0.0f;
#pragma unroll
      for (int c = 0; c < 13; ++c) p1[c] = 0.0f;
    }
  }
  __syncthreads();

  gauss_jordan<24>(g0, g1, piv, t);
#pragma unroll
  for (int c = 0; c < 12; ++c) sGi[e * GS + t * 12 + c] = g0[12 + c];
  if (t < 4) {
#pragma unroll
    for (int c = 0; c < 12; ++c) sGi[e * GS + (t + 8) * 12 + c] = g1[12 + c];
  }

  gauss_jordan<13>(p0, p1, piv, t);   // internal barriers publish Ginv too
  sAux[e * SS + t] = p0[12];
  if (t < 4) sAux[e * SS + t + 8] = p1[12];
  __syncthreads();                    // tsol visible in sAux[0..11]

  float bown0 = b[(size_t)env * 24 + r0w];
  float bown1 = b[(size_t)env * 24 + r0w + 1];
  float bown2 = b[(size_t)env * 24 + r0w + 2];
  float cfr0  = cf[(size_t)env * 24 + r0w];
  float cfr1  = cf[(size_t)env * 24 + r0w + 1];
  float cfr2  = cf[(size_t)env * 24 + r0w + 2];

  // ---- Fm rows as NAMED float4 chunks (never an indexable array) ----
  Row6 F0 = build_row(myH, giB, auxB, r0w + 0);
  Row6 F1 = build_row(myH, giB, auxB, r0w + 1);
  Row6 F2 = build_row(myH, giB, auxB, r0w + 2);
  __syncthreads();                    // tsol reads done
  sAux[e * SS + r0w]     = F0.v - bown0;
  sAux[e * SS + r0w + 1] = F1.v - bown1;
  sAux[e * SS + r0w + 2] = F2.v - bown2;
  __syncthreads();                    // v visible
  float mu0 = 0.f, mu1 = 0.f, mu2 = 0.f;
  {
    const float4* av = (const float4*)auxB;
    float4 a;
    a = av[0]; FMA4(mu0, F0.c0, a); FMA4(mu1, F1.c0, a); FMA4(mu2, F2.c0, a);
    a = av[1]; FMA4(mu0, F0.c1, a); FMA4(mu1, F1.c1, a); FMA4(mu2, F2.c1, a);
    a = av[2]; FMA4(mu0, F0.c2, a); FMA4(mu1, F1.c2, a); FMA4(mu2, F2.c2, a);
    a = av[3]; FMA4(mu0, F0.c3, a); FMA4(mu1, F1.c3, a); FMA4(mu2, F2.c3, a);
    a = av[4]; FMA4(mu0, F0.c4, a); FMA4(mu1, F1.c4, a); FMA4(mu2, F2.c4, a);
    a = av[5]; FMA4(mu0, F0.c5, a); FMA4(mu1, F1.c5, a); FMA4(mu2, F2.c5, a);
  }

  // ---- iterations: all state in named scalars/float4s ----
  float l0 = 0.f, l1 = 0.f, l2 = 0.f, z0 = 0.f, z1 = 0.f, z2 = 0.f;
  int buf = 0;
  for (int it = 0; it < niter; ++it) {
    float s0 = l0 + z0, s1 = l1 + z1, s2 = l2 + z2;
    float* sw = &sS[buf * (EPB * SS) + e * SS];
    sw[r0w] = s0; sw[r0w + 1] = s1; sw[r0w + 2] = s2;
    __syncthreads();                  // one barrier/iter (double-buffered s)
    const float4* sv = (const float4*)sw;
    float w0 = mu0, w1 = mu1, w2 = mu2;
    float4 sj;
    sj = sv[0]; FMA4(w0, F0.c0, sj); FMA4(w1, F1.c0, sj); FMA4(w2, F2.c0, sj);
    sj = sv[1]; FMA4(w0, F0.c1, sj); FMA4(w1, F1.c1, sj); FMA4(w2, F2.c1, sj);
    sj = sv[2]; FMA4(w0, F0.c2, sj); FMA4(w1, F1.c2, sj); FMA4(w2, F2.c2, sj);
    sj = sv[3]; FMA4(w0, F0.c3, sj); FMA4(w1, F1.c3, sj); FMA4(w2, F2.c3, sj);
    sj = sv[4]; FMA4(w0, F0.c4, sj); FMA4(w1, F1.c4, sj); FMA4(w2, F2.c4, sj);
    sj = sv[5]; FMA4(w0, F0.c5, sj); FMA4(w1, F1.c5, sj); FMA4(w2, F2.c5, sj);
    float zp0 = fmaf(-2.0f, w0, s0);
    float zp1 = fmaf(-2.0f, w1, s1);
    float zp2 = fmaf(-2.0f, w2, s2);
    l0 = w0; l1 = w1; l2 = w2;
    if (t < 4) {                      // SOC cone t (rows 3t..3t+2, thread-local)
      float m = (zp2 > 0.0f) ? 1.0f : 0.0f;
      z0 = zp0 * m * cfr0; z1 = zp1 * m * cfr1; z2 = zp2 * m * cfr2;
    } else {                          // box rows 12..23
      z0 = fminf(fmaxf(zp0, -10.0f), 10.0f) * cfr0;
      z1 = fminf(fmaxf(zp1, -10.0f), 10.0f) * cfr1;
      z2 = fminf(fmaxf(zp2, -10.0f), 10.0f) * cfr2;
    }
    buf ^= 1;
  }

  // ---- outputs: lz, then x = (HtH)^-1 Ht (z - b) ----
  float* xout  = out;
  float* lzout = out + (size_t)Btot * 12;
  lzout[(size_t)env * 48 + r0w]          = l0;
  lzout[(size_t)env * 48 + r0w + 1]      = l1;
  lzout[(size_t)env * 48 + r0w + 2]      = l2;
  lzout[(size_t)env * 48 + 24 + r0w]     = z0;
  lzout[(size_t)env * 48 + 24 + r0w + 1] = z1;
  lzout[(size_t)env * 48 + 24 + r0w + 2] = z2;
  __syncthreads();
  sAux[e * SS + r0w]     = z0 - bown0;
  sAux[e * SS + r0w + 1] = z1 - bown1;
  sAux[e * SS + r0w + 2] = z2 - bown2;
  __syncthreads();

  float h0[13], h1[13];
  {
    float hr[24];
#pragma unroll
    for (int k = 0; k < 24; ++k) hr[k] = myH[k * 12 + t];
#pragma unroll
    for (int c = 0; c < 12; ++c) {
      float acc = 0.f;
#pragma unroll
      for (int k = 0; k < 24; ++k) acc = fmaf(hr[k], myH[k * 12 + c], acc);
      h0[c] = acc;
    }
    float accu = 0.f;
#pragma unroll
    for (int k = 0; k < 24; ++k) accu = fmaf(hr[k], sAux[e * SS + k], accu);
    h0[12] = accu;
    if (t < 4) {
      float hr2[24];
#pragma unroll
      for (int k = 0; k < 24; ++k) hr2[k] = myH[k * 12 + t + 8];
#pragma unroll
      for (int c = 0; c < 12; ++c) {
        float a2 = 0.f;
#pragma unroll
        for (int k = 0; k < 24; ++k) a2 = fmaf(hr2[k], myH[k * 12 + c], a2);
        h1[c] = a2;
      }
      float a3 = 0.f;
#pragma unroll
      for (int k = 0; k < 24; ++k) a3 = fmaf(hr2[k], sAux[e * SS + k], a3);
      h1[12] = a3;
    } else {
#pragma unroll
      for (int c = 0; c < 13; ++c) h1[c] = 0.f;
    }
  }
  __syncthreads();
  gauss_jordan<13>(h0, h1, piv, t);
  xout[(size_t)env * 12 + t] = h0[12];
  if (t < 4) xout[(size_t)env * 12 + t + 8] = h1[12];
}

extern "C" void kernel_launch(void* const* d_in, const int* in_sizes, int n_in,
                              void* d_out, int out_size, void* d_ws, size_t ws_size,
                              hipStream_t stream) {
  const float* P  = (const float*)d_in[0];
  const float* q  = (const float*)d_in[1];
  const float* H  = (const float*)d_in[2];
  const float* b  = (const float*)d_in[3];
  const float* cf = (const float*)d_in[4];
  const int*   it = (const int*)d_in[5];
  float* out = (float*)d_out;
  const int B = in_sizes[1] / 12;       // q is [B,12]
  const int grid = B / EPB;             // 16384/32 = 512 blocks
  pdhg_kernel<<<grid, BLOCK, 0, stream>>>(P, q, H, b, cf, it, out, B);
}

// Round 6
// 206.623 us; speedup vs baseline: 1.9202x; 1.1328x over previous
//
#include <hip/hip_runtime.h>

#define EPB 32          // envs per block
#define BLOCK 256       // 8 threads/env * 32 envs
#define HS 292          // H LDS stride (288 + 4 pad), 1168 B = 73*16 aligned
#define GS 148          // G/Ginv LDS stride (144 + 4 pad), 592 B = 37*16 aligned
#define SS 28           // q/y/aux/s stride (24 + 4 pad), 112 B = 7*16 aligned

// acc += dot(f4, s4)
#define FMA4(acc, f, s)                                         \
  acc = fmaf((f).x, (s).x,                                      \
        fmaf((f).y, (s).y,                                      \
        fmaf((f).z, (s).z,                                      \
        fmaf((f).w, (s).w, (acc)))))

// acc4 += s * v4 (scalar * float4)
#define VFMA(acc, s, v)                                         \
  { (acc).x = fmaf((s), (v).x, (acc).x);                        \
    (acc).y = fmaf((s), (v).y, (acc).y);                        \
    (acc).z = fmaf((s), (v).z, (acc).z);                        \
    (acc).w = fmaf((s), (v).w, (acc).w); }

struct Row6 { float4 c0, c1, c2, c3, c4, c5; };   // one Fm row, named chunks

template<int K>
__device__ __forceinline__ float getel(const float4& a, const float4& b, const float4& c) {
  if constexpr (K == 0) return a.x; else if constexpr (K == 1) return a.y;
  else if constexpr (K == 2) return a.z; else if constexpr (K == 3) return a.w;
  else if constexpr (K == 4) return b.x; else if constexpr (K == 5) return b.y;
  else if constexpr (K == 6) return b.z; else if constexpr (K == 7) return b.w;
  else if constexpr (K == 8) return c.x; else if constexpr (K == 9) return c.y;
  else if constexpr (K == 10) return c.z; else return c.w;
}
template<int K>
__device__ __forceinline__ void setel(float4& a, float4& b, float4& c, float v) {
  if constexpr (K == 0) a.x = v; else if constexpr (K == 1) a.y = v;
  else if constexpr (K == 2) a.z = v; else if constexpr (K == 3) a.w = v;
  else if constexpr (K == 4) b.x = v; else if constexpr (K == 5) b.y = v;
  else if constexpr (K == 6) b.z = v; else if constexpr (K == 7) b.w = v;
  else if constexpr (K == 8) c.x = v; else if constexpr (K == 9) c.y = v;
  else if constexpr (K == 10) c.z = v; else c.w = v;
}

// One pivot step of in-place Gauss-Jordan inversion (NR gaussj, no pivoting;
// valid for SPD). A: LDS 12x12 row-major stride 12. Thread t owns rows t and
// (t<4) t+8. All state in LDS or named registers -> nothing can spill.
template<int K>
__device__ __forceinline__ void gj_step(float* A, int t) {
  if (t == K || t + 8 == K) {               // scale pivot row; A[K][K] <- 1/p
    float4* r = (float4*)(A + K * 12);
    float4 a = r[0], b = r[1], c = r[2];
    float ip = 1.0f / getel<K>(a, b, c);
    setel<K>(a, b, c, 1.0f);
    a.x *= ip; a.y *= ip; a.z *= ip; a.w *= ip;
    b.x *= ip; b.y *= ip; b.z *= ip; b.w *= ip;
    c.x *= ip; c.y *= ip; c.z *= ip; c.w *= ip;
    r[0] = a; r[1] = b; r[2] = c;
  }
  __syncthreads();
  const float4* pr = (const float4*)(A + K * 12);
  float4 p0 = pr[0], p1 = pr[1], p2 = pr[2];
  {
    float4* rr = (float4*)(A + t * 12);
    float4 a = rr[0], b = rr[1], c = rr[2];
    float f = getel<K>(a, b, c);
    if (t == K) f = 0.0f; else setel<K>(a, b, c, 0.0f);
    a.x = fmaf(-f, p0.x, a.x); a.y = fmaf(-f, p0.y, a.y);
    a.z = fmaf(-f, p0.z, a.z); a.w = fmaf(-f, p0.w, a.w);
    b.x = fmaf(-f, p1.x, b.x); b.y = fmaf(-f, p1.y, b.y);
    b.z = fmaf(-f, p1.z, b.z); b.w = fmaf(-f, p1.w, b.w);
    c.x = fmaf(-f, p2.x, c.x); c.y = fmaf(-f, p2.y, c.y);
    c.z = fmaf(-f, p2.z, c.z); c.w = fmaf(-f, p2.w, c.w);
    rr[0] = a; rr[1] = b; rr[2] = c;
  }
  if (t < 4) {
    const int i = t + 8;
    float4* rr = (float4*)(A + i * 12);
    float4 a = rr[0], b = rr[1], c = rr[2];
    float f = getel<K>(a, b, c);
    if (i == K) f = 0.0f; else setel<K>(a, b, c, 0.0f);
    a.x = fmaf(-f, p0.x, a.x); a.y = fmaf(-f, p0.y, a.y);
    a.z = fmaf(-f, p0.z, a.z); a.w = fmaf(-f, p0.w, a.w);
    b.x = fmaf(-f, p1.x, b.x); b.y = fmaf(-f, p1.y, b.y);
    b.z = fmaf(-f, p1.z, b.z); b.w = fmaf(-f, p1.w, b.w);
    c.x = fmaf(-f, p2.x, c.x); c.y = fmaf(-f, p2.y, c.y);
    c.z = fmaf(-f, p2.z, c.z); c.w = fmaf(-f, p2.w, c.w);
    rr[0] = a; rr[1] = b; rr[2] = c;
  }
  __syncthreads();
}
template<int K>
__device__ __forceinline__ void gj_all(float* A, int t) {
  gj_step<K>(A, t);
  if constexpr (K < 11) gj_all<K + 1>(A, t);
}

__device__ __forceinline__ float dot12(float4 a0, float4 a1, float4 a2,
                                       const float* p) {
  const float4* p4 = (const float4*)p;
  float4 b0 = p4[0], b1 = p4[1], b2 = p4[2];
  float acc = 0.f;
  FMA4(acc, a0, b0); FMA4(acc, a1, b1); FMA4(acc, a2, b2);
  return acc;
}

__device__ __forceinline__ float dot24(const Row6& F, const float* p) {
  const float4* p4 = (const float4*)p;
  float acc = 0.f;
  float4 v;
  v = p4[0]; FMA4(acc, F.c0, v);
  v = p4[1]; FMA4(acc, F.c1, v);
  v = p4[2]; FMA4(acc, F.c2, v);
  v = p4[3]; FMA4(acc, F.c3, v);
  v = p4[4]; FMA4(acc, F.c4, v);
  v = p4[5]; FMA4(acc, F.c5, v);
  return acc;
}

// Gram row i of HtH (optionally + P already resident in gi) -> gi row i.
// Each row written only by its owner thread; reads sH + own gi row.
__device__ __forceinline__ void build_gram_row(const float* myH, float* gi,
                                               int i, bool addP) {
  float4 a0 = {0,0,0,0}, a1 = {0,0,0,0}, a2 = {0,0,0,0};
#pragma unroll
  for (int k = 0; k < 24; ++k) {
    float coef = myH[k * 12 + i];
    const float4* hk = (const float4*)(myH + k * 12);
    float4 h0 = hk[0], h1 = hk[1], h2 = hk[2];
    VFMA(a0, coef, h0); VFMA(a1, coef, h1); VFMA(a2, coef, h2);
  }
  float4* g = (float4*)(gi + i * 12);
  if (addP) {
    float4 q0 = g[0], q1 = g[1], q2 = g[2];
    a0.x += q0.x; a0.y += q0.y; a0.z += q0.z; a0.w += q0.w;
    a1.x += q1.x; a1.y += q1.y; a1.z += q1.z; a1.w += q1.w;
    a2.x += q2.x; a2.y += q2.y; a2.z += q2.z; a2.w += q2.w;
  }
  g[0] = a0; g[1] = a1; g[2] = a2;
}

// Fm row r = e_r - (H[r,:]*Ginv)*H^T, all named values.
__device__ __forceinline__ Row6 build_row(const float* myH, const float* gi, int r) {
  const float4* hr4 = (const float4*)(myH + r * 12);
  float4 h0 = hr4[0], h1 = hr4[1], h2 = hr4[2];
  float4 gA = {0,0,0,0}, gB = {0,0,0,0}, gC = {0,0,0,0};
#define ACC_G(c, coef)                                          \
  { const float4* g4 = (const float4*)(gi + (c) * 12);          \
    float4 r0 = g4[0], r1 = g4[1], r2 = g4[2];                  \
    VFMA(gA, coef, r0); VFMA(gB, coef, r1); VFMA(gC, coef, r2); }
  ACC_G(0, h0.x) ACC_G(1, h0.y) ACC_G(2,  h0.z) ACC_G(3,  h0.w)
  ACC_G(4, h1.x) ACC_G(5, h1.y) ACC_G(6,  h1.z) ACC_G(7,  h1.w)
  ACC_G(8, h2.x) ACC_G(9, h2.y) ACC_G(10, h2.z) ACC_G(11, h2.w)
#undef ACC_G
  Row6 R;
#define FEL(j) ((((j) == r) ? 1.0f : 0.0f) - dot12(gA, gB, gC, myH + (j) * 12))
  R.c0 = make_float4(FEL(0),  FEL(1),  FEL(2),  FEL(3));
  R.c1 = make_float4(FEL(4),  FEL(5),  FEL(6),  FEL(7));
  R.c2 = make_float4(FEL(8),  FEL(9),  FEL(10), FEL(11));
  R.c3 = make_float4(FEL(12), FEL(13), FEL(14), FEL(15));
  R.c4 = make_float4(FEL(16), FEL(17), FEL(18), FEL(19));
  R.c5 = make_float4(FEL(20), FEL(21), FEL(22), FEL(23));
#undef FEL
  return R;
}

__global__ __launch_bounds__(BLOCK, 2)
void pdhg_kernel(const float* __restrict__ P, const float* __restrict__ q,
                 const float* __restrict__ H, const float* __restrict__ b,
                 const float* __restrict__ cf, const int* __restrict__ itp,
                 float* __restrict__ out, int Btot) {
  __shared__ __align__(16) float sH[EPB * HS];
  __shared__ __align__(16) float sGi[EPB * GS];      // P -> G -> Ginv -> HtH -> (HtH)^-1
  __shared__ __align__(16) float sS[2 * EPB * SS];   // s dbl-buf; buf1 stages b pre-loop
  __shared__ __align__(16) float sAux[EPB * SS];     // q | y, later z-b | rv

  const int tid = threadIdx.x;
  const int e   = tid >> 3;
  const int t   = tid & 7;
  const int env = blockIdx.x * EPB + e;
  const int niter = itp[0];
  const int r0w = 3 * t;

  // ---- coalesced float4 staging: H, P, q, b ----
  {
    const float4* gH = (const float4*)(H + (size_t)blockIdx.x * EPB * 288);
    for (int i = tid; i < EPB * 72; i += BLOCK) {
      int ee = i / 72, off = i - ee * 72;
      *(float4*)&sH[ee * HS + off * 4] = gH[i];
    }
    const float4* gP = (const float4*)(P + (size_t)blockIdx.x * EPB * 144);
    for (int i = tid; i < EPB * 36; i += BLOCK) {
      int ee = i / 36, off = i - ee * 36;
      *(float4*)&sGi[ee * GS + off * 4] = gP[i];
    }
    const float4* gq = (const float4*)(q + (size_t)blockIdx.x * EPB * 12);
    if (tid < EPB * 3) {                      // 96 float4s
      int ee = tid / 3, off = tid - ee * 3;
      *(float4*)&sAux[ee * SS + off * 4] = gq[tid];
    }
    const float4* gb = (const float4*)(b + (size_t)blockIdx.x * EPB * 24);
    if (tid < EPB * 6) {                      // 192 float4s -> sS buf1
      int ee = tid / 6, off = tid - ee * 6;
      *(float4*)&sS[EPB * SS + ee * SS + off * 4] = gb[tid];
    }
  }
  __syncthreads();

  const float* myH = &sH[e * HS];
  float* giB = &sGi[e * GS];
  float* auxB = &sAux[e * SS];
  const float* bB = &sS[EPB * SS + e * SS];

  // ---- G = P + HtH (rows t, t+8), then invert in place in LDS ----
  build_gram_row(myH, giB, t, true);
  if (t < 4) build_gram_row(myH, giB, t + 8, true);
  __syncthreads();
  gj_all<0>(giB, t);                          // giB now = Ginv (24 internal barriers)

  // ---- y = Ginv * q  (q in aux[0..11], y -> aux[12..23]) ----
  {
    const float4* gr = (const float4*)(giB + t * 12);
    auxB[12 + t] = dot12(gr[0], gr[1], gr[2], auxB);
    if (t < 4) {
      const float4* gr8 = (const float4*)(giB + (t + 8) * 12);
      auxB[12 + t + 8] = dot12(gr8[0], gr8[1], gr8[2], auxB);
    }
  }
  __syncthreads();

  // ---- Fm rows (named), u = H*y, mu = u - Fm*b  (Woodbury: no P-solve) ----
  Row6 F0 = build_row(myH, giB, r0w + 0);
  Row6 F1 = build_row(myH, giB, r0w + 1);
  Row6 F2 = build_row(myH, giB, r0w + 2);
  float mu0, mu1, mu2;
  {
    const float4* h0 = (const float4*)(myH + (r0w + 0) * 12);
    const float4* h1 = (const float4*)(myH + (r0w + 1) * 12);
    const float4* h2 = (const float4*)(myH + (r0w + 2) * 12);
    const float* y = auxB + 12;
    mu0 = dot12(h0[0], h0[1], h0[2], y) - dot24(F0, bB);
    mu1 = dot12(h1[0], h1[1], h1[2], y) - dot24(F1, bB);
    mu2 = dot12(h2[0], h2[1], h2[2], y) - dot24(F2, bB);
  }
  float cfr0 = cf[(size_t)env * 24 + r0w];
  float cfr1 = cf[(size_t)env * 24 + r0w + 1];
  float cfr2 = cf[(size_t)env * 24 + r0w + 2];

  // ---- iterations: s = l+z; w = Fm s + mu; l = w; z = proj(s-2w)*cf ----
  float l0 = 0.f, l1 = 0.f, l2 = 0.f, z0 = 0.f, z1 = 0.f, z2 = 0.f;
  int buf = 0;
  for (int it = 0; it < niter; ++it) {
    float s0 = l0 + z0, s1 = l1 + z1, s2 = l2 + z2;
    float* sw = &sS[buf * (EPB * SS) + e * SS];
    sw[r0w] = s0; sw[r0w + 1] = s1; sw[r0w + 2] = s2;
    __syncthreads();                  // one barrier/iter (double-buffered s)
    float w0 = mu0 + dot24(F0, sw);
    float w1 = mu1 + dot24(F1, sw);
    float w2 = mu2 + dot24(F2, sw);
    float zp0 = fmaf(-2.0f, w0, s0);
    float zp1 = fmaf(-2.0f, w1, s1);
    float zp2 = fmaf(-2.0f, w2, s2);
    l0 = w0; l1 = w1; l2 = w2;
    if (t < 4) {                      // SOC cone t (rows 3t..3t+2, thread-local)
      float m = (zp2 > 0.0f) ? 1.0f : 0.0f;
      z0 = zp0 * m * cfr0; z1 = zp1 * m * cfr1; z2 = zp2 * m * cfr2;
    } else {                          // box rows 12..23
      z0 = fminf(fmaxf(zp0, -10.0f), 10.0f) * cfr0;
      z1 = fminf(fmaxf(zp1, -10.0f), 10.0f) * cfr1;
      z2 = fminf(fmaxf(zp2, -10.0f), 10.0f) * cfr2;
    }
    buf ^= 1;
  }

  // ---- outputs: lz, then x = (HtH)^-1 Ht (z - b), all in LDS ----
  float* xout  = out;
  float* lzout = out + (size_t)Btot * 12;
  lzout[(size_t)env * 48 + r0w]          = l0;
  lzout[(size_t)env * 48 + r0w + 1]      = l1;
  lzout[(size_t)env * 48 + r0w + 2]      = l2;
  lzout[(size_t)env * 48 + 24 + r0w]     = z0;
  lzout[(size_t)env * 48 + 24 + r0w + 1] = z1;
  lzout[(size_t)env * 48 + 24 + r0w + 2] = z2;

  float bo0 = b[(size_t)env * 24 + r0w];
  float bo1 = b[(size_t)env * 24 + r0w + 1];
  float bo2 = b[(size_t)env * 24 + r0w + 2];
  __syncthreads();                    // pre-loop/loop readers of sAux done
  auxB[r0w]     = z0 - bo0;
  auxB[r0w + 1] = z1 - bo1;
  auxB[r0w + 2] = z2 - bo2;
  __syncthreads();                    // z-b visible

  // rv = Ht(z-b); HtH -> sGi (overwrites Ginv, no longer needed)
  float rv0 = 0.f, rv8 = 0.f;
  {
#pragma unroll
    for (int k = 0; k < 24; ++k) rv0 = fmaf(myH[k * 12 + t], auxB[k], rv0);
    if (t < 4) {
#pragma unroll
      for (int k = 0; k < 24; ++k) rv8 = fmaf(myH[k * 12 + t + 8], auxB[k], rv8);
    }
  }
  build_gram_row(myH, giB, t, false);
  if (t < 4) build_gram_row(myH, giB, t + 8, false);
  // same-wave lockstep: all 8 lanes of this env finished reading auxB above
  // before any lane's store below issues (LDS ops are in program order).
  auxB[t] = rv0;
  if (t < 4) auxB[t + 8] = rv8;
  __syncthreads();                    // HtH + rv visible

  gj_all<0>(giB, t);                  // (HtH)^-1 in place
  {
    const float4* gr = (const float4*)(giB + t * 12);
    xout[(size_t)env * 12 + t] = dot12(gr[0], gr[1], gr[2], auxB);
    if (t < 4) {
      const float4* gr8 = (const float4*)(giB + (t + 8) * 12);
      xout[(size_t)env * 12 + t + 8] = dot12(gr8[0], gr8[1], gr8[2], auxB);
    }
  }
}

extern "C" void kernel_launch(void* const* d_in, const int* in_sizes, int n_in,
                              void* d_out, int out_size, void* d_ws, size_t ws_size,
                              hipStream_t stream) {
  const float* P  = (const float*)d_in[0];
  const float* q  = (const float*)d_in[1];
  const float* H  = (const float*)d_in[2];
  const float* b  = (const float*)d_in[3];
  const float* cf = (const float*)d_in[4];
  const int*   it = (const int*)d_in[5];
  float* out = (float*)d_out;
  const int B = in_sizes[1] / 12;       // q is [B,12]
  const int grid = B / EPB;             // 16384/32 = 512 blocks, 2 blocks/CU
  pdhg_kernel<<<grid, BLOCK, 0, stream>>>(P, q, H, b, cf, it, out, B);
}

// Round 8
// 156.749 us; speedup vs baseline: 2.5312x; 1.3182x over previous
//
#include <hip/hip_runtime.h>

#define EPB 8           // envs per block
#define BLOCK 64        // ONE wave: every env (8 lanes) is wave-internal
#define HS 292          // H LDS stride (288 + 4)
#define GS 148          // G/Ginv LDS stride (144 + 4)
#define SS 28           // s / aux stride (24 + 4)

#define WFENCE() __builtin_amdgcn_wave_barrier()   // compiler fence, 0 instr

// acc += dot(f4, s4)
#define FMA4(acc, f, s)                                         \
  acc = fmaf((f).x, (s).x,                                      \
        fmaf((f).y, (s).y,                                      \
        fmaf((f).z, (s).z,                                      \
        fmaf((f).w, (s).w, (acc)))))

// acc4 += s * v4
#define VFMA(acc, s, v)                                         \
  { (acc).x = fmaf((s), (v).x, (acc).x);                        \
    (acc).y = fmaf((s), (v).y, (acc).y);                        \
    (acc).z = fmaf((s), (v).z, (acc).z);                        \
    (acc).w = fmaf((s), (v).w, (acc).w); }

struct Row6 { float4 c0, c1, c2, c3, c4, c5; };

template<int K>
__device__ __forceinline__ float getel(const float4& a, const float4& b, const float4& c) {
  if constexpr (K == 0) return a.x; else if constexpr (K == 1) return a.y;
  else if constexpr (K == 2) return a.z; else if constexpr (K == 3) return a.w;
  else if constexpr (K == 4) return b.x; else if constexpr (K == 5) return b.y;
  else if constexpr (K == 6) return b.z; else if constexpr (K == 7) return b.w;
  else if constexpr (K == 8) return c.x; else if constexpr (K == 9) return c.y;
  else if constexpr (K == 10) return c.z; else return c.w;
}
template<int K>
__device__ __forceinline__ void setel(float4& a, float4& b, float4& c, float v) {
  if constexpr (K == 0) a.x = v; else if constexpr (K == 1) a.y = v;
  else if constexpr (K == 2) a.z = v; else if constexpr (K == 3) a.w = v;
  else if constexpr (K == 4) b.x = v; else if constexpr (K == 5) b.y = v;
  else if constexpr (K == 6) b.z = v; else if constexpr (K == 7) b.w = v;
  else if constexpr (K == 8) c.x = v; else if constexpr (K == 9) c.y = v;
  else if constexpr (K == 10) c.z = v; else c.w = v;
}

// In-place Gauss-Jordan inversion step in LDS (SPD, no pivoting). Wave-internal:
// pivot write -> reads ordered by per-wave in-order DS + compiler aliasing.
template<int K>
__device__ __forceinline__ void gj_step(float* A, int t) {
  if (t == K || t + 8 == K) {
    float4* r = (float4*)(A + K * 12);
    float4 a = r[0], b = r[1], c = r[2];
    float ip = 1.0f / getel<K>(a, b, c);
    setel<K>(a, b, c, 1.0f);
    a.x *= ip; a.y *= ip; a.z *= ip; a.w *= ip;
    b.x *= ip; b.y *= ip; b.z *= ip; b.w *= ip;
    c.x *= ip; c.y *= ip; c.z *= ip; c.w *= ip;
    r[0] = a; r[1] = b; r[2] = c;
  }
  WFENCE();
  const float4* pr = (const float4*)(A + K * 12);
  float4 p0 = pr[0], p1 = pr[1], p2 = pr[2];
  {
    float4* rr = (float4*)(A + t * 12);
    float4 a = rr[0], b = rr[1], c = rr[2];
    float f = getel<K>(a, b, c);
    if (t == K) f = 0.0f; else setel<K>(a, b, c, 0.0f);
    a.x = fmaf(-f, p0.x, a.x); a.y = fmaf(-f, p0.y, a.y);
    a.z = fmaf(-f, p0.z, a.z); a.w = fmaf(-f, p0.w, a.w);
    b.x = fmaf(-f, p1.x, b.x); b.y = fmaf(-f, p1.y, b.y);
    b.z = fmaf(-f, p1.z, b.z); b.w = fmaf(-f, p1.w, b.w);
    c.x = fmaf(-f, p2.x, c.x); c.y = fmaf(-f, p2.y, c.y);
    c.z = fmaf(-f, p2.z, c.z); c.w = fmaf(-f, p2.w, c.w);
    rr[0] = a; rr[1] = b; rr[2] = c;
  }
  if (t < 4) {
    const int i = t + 8;
    float4* rr = (float4*)(A + i * 12);
    float4 a = rr[0], b = rr[1], c = rr[2];
    float f = getel<K>(a, b, c);
    if (i == K) f = 0.0f; else setel<K>(a, b, c, 0.0f);
    a.x = fmaf(-f, p0.x, a.x); a.y = fmaf(-f, p0.y, a.y);
    a.z = fmaf(-f, p0.z, a.z); a.w = fmaf(-f, p0.w, a.w);
    b.x = fmaf(-f, p1.x, b.x); b.y = fmaf(-f, p1.y, b.y);
    b.z = fmaf(-f, p1.z, b.z); b.w = fmaf(-f, p1.w, b.w);
    c.x = fmaf(-f, p2.x, c.x); c.y = fmaf(-f, p2.y, c.y);
    c.z = fmaf(-f, p2.z, c.z); c.w = fmaf(-f, p2.w, c.w);
    rr[0] = a; rr[1] = b; rr[2] = c;
  }
  WFENCE();
}
template<int K>
__device__ __forceinline__ void gj_all(float* A, int t) {
  gj_step<K>(A, t);
  if constexpr (K < 11) gj_all<K + 1>(A, t);
}

__device__ __forceinline__ float dot12(float4 a0, float4 a1, float4 a2,
                                       const float* p) {
  const float4* p4 = (const float4*)p;
  float4 b0 = p4[0], b1 = p4[1], b2 = p4[2];
  float acc = 0.f;
  FMA4(acc, a0, b0); FMA4(acc, a1, b1); FMA4(acc, a2, b2);
  return acc;
}

__device__ __forceinline__ void build_gram_row(const float* myH, float* gi,
                                               int i, bool addP) {
  float4 a0 = {0,0,0,0}, a1 = {0,0,0,0}, a2 = {0,0,0,0};
#pragma unroll
  for (int k = 0; k < 24; ++k) {
    float coef = myH[k * 12 + i];
    const float4* hk = (const float4*)(myH + k * 12);
    float4 h0 = hk[0], h1 = hk[1], h2 = hk[2];
    VFMA(a0, coef, h0); VFMA(a1, coef, h1); VFMA(a2, coef, h2);
  }
  float4* g = (float4*)(gi + i * 12);
  if (addP) {
    float4 q0 = g[0], q1 = g[1], q2 = g[2];
    a0.x += q0.x; a0.y += q0.y; a0.z += q0.z; a0.w += q0.w;
    a1.x += q1.x; a1.y += q1.y; a1.z += q1.z; a1.w += q1.w;
    a2.x += q2.x; a2.y += q2.y; a2.z += q2.z; a2.w += q2.w;
  }
  g[0] = a0; g[1] = a1; g[2] = a2;
}

__device__ __forceinline__ Row6 build_row(const float* myH, const float* gi, int r) {
  const float4* hr4 = (const float4*)(myH + r * 12);
  float4 h0 = hr4[0], h1 = hr4[1], h2 = hr4[2];
  float4 gA = {0,0,0,0}, gB = {0,0,0,0}, gC = {0,0,0,0};
#define ACC_G(c, coef)                                          \
  { const float4* g4 = (const float4*)(gi + (c) * 12);          \
    float4 r0 = g4[0], r1 = g4[1], r2 = g4[2];                  \
    VFMA(gA, coef, r0); VFMA(gB, coef, r1); VFMA(gC, coef, r2); }
  ACC_G(0, h0.x) ACC_G(1, h0.y) ACC_G(2,  h0.z) ACC_G(3,  h0.w)
  ACC_G(4, h1.x) ACC_G(5, h1.y) ACC_G(6,  h1.z) ACC_G(7,  h1.w)
  ACC_G(8, h2.x) ACC_G(9, h2.y) ACC_G(10, h2.z) ACC_G(11, h2.w)
#undef ACC_G
  Row6 R;
#define FEL(j) ((((j) == r) ? 1.0f : 0.0f) - dot12(gA, gB, gC, myH + (j) * 12))
  R.c0 = make_float4(FEL(0),  FEL(1),  FEL(2),  FEL(3));
  R.c1 = make_float4(FEL(4),  FEL(5),  FEL(6),  FEL(7));
  R.c2 = make_float4(FEL(8),  FEL(9),  FEL(10), FEL(11));
  R.c3 = make_float4(FEL(12), FEL(13), FEL(14), FEL(15));
  R.c4 = make_float4(FEL(16), FEL(17), FEL(18), FEL(19));
  R.c5 = make_float4(FEL(20), FEL(21), FEL(22), FEL(23));
#undef FEL
  return R;
}

__global__ __launch_bounds__(BLOCK)
void pdhg_kernel(const float* __restrict__ P, const float* __restrict__ q,
                 const float* __restrict__ H, const float* __restrict__ b,
                 const float* __restrict__ cf, const int* __restrict__ itp,
                 float* __restrict__ out, int Btot) {
  __shared__ __align__(16) float sH[EPB * HS];
  __shared__ __align__(16) float sGi[EPB * GS];   // P -> G -> Ginv -> HtH -> inv
  __shared__ __align__(16) float sS[EPB * SS];    // b pre-loop, then s (single buf)
  __shared__ __align__(16) float sAux[EPB * SS];  // q|y, later z-b

  const int tid = threadIdx.x;                    // 0..63, one wave
  const int e   = tid >> 3;
  const int t   = tid & 7;
  const int env = blockIdx.x * EPB + e;
  const int niter = itp[0];
  const int r0w = 3 * t;

  // ---- per-wave float4 staging: H, P, q, b ----
  {
    const float4* gH = (const float4*)(H + (size_t)blockIdx.x * EPB * 288);
#pragma unroll
    for (int rep = 0; rep < 9; ++rep) {           // 8*72 = 576 float4
      int i = tid + rep * 64;
      int ee = i / 72, off = i - ee * 72;
      *(float4*)&sH[ee * HS + off * 4] = gH[i];
    }
    const float4* gP = (const float4*)(P + (size_t)blockIdx.x * EPB * 144);
#pragma unroll
    for (int rep = 0; rep < 4; ++rep) {           // 8*36 = 288 float4
      int i = tid + rep * 64;
      int ee = i / 36, off = i - ee * 36;
      *(float4*)&sGi[ee * GS + off * 4] = gP[i];
    }
    { int i = tid + 256; if (tid < 32) {
        int ee = i / 36, off = i - ee * 36;
        *(float4*)&sGi[ee * GS + off * 4] = gP[i]; } }
    const float4* gq = (const float4*)(q + (size_t)blockIdx.x * EPB * 12);
    if (tid < EPB * 3) {
      int ee = tid / 3, off = tid - ee * 3;
      *(float4*)&sAux[ee * SS + off * 4] = gq[tid];
    }
    const float4* gb = (const float4*)(b + (size_t)blockIdx.x * EPB * 24);
    if (tid < EPB * 6) {
      int ee = tid / 6, off = tid - ee * 6;
      *(float4*)&sS[ee * SS + off * 4] = gb[tid];
    }
  }
  WFENCE();

  const float* myH = &sH[e * HS];
  float* giB = &sGi[e * GS];
  float* auxB = &sAux[e * SS];
  const float* bB = &sS[e * SS];

  // ---- G = P + HtH; invert in place (wave-internal, no barriers) ----
  build_gram_row(myH, giB, t, true);
  if (t < 4) build_gram_row(myH, giB, t + 8, true);
  WFENCE();
  gj_all<0>(giB, t);

  // ---- y = Ginv * q ----
  {
    const float4* gr = (const float4*)(giB + t * 12);
    auxB[12 + t] = dot12(gr[0], gr[1], gr[2], auxB);
    if (t < 4) {
      const float4* gr8 = (const float4*)(giB + (t + 8) * 12);
      auxB[12 + t + 8] = dot12(gr8[0], gr8[1], gr8[2], auxB);
    }
  }
  WFENCE();

  // ---- Fm rows (named float4s), mu = H*y - Fm*b ----
  Row6 F0 = build_row(myH, giB, r0w + 0);
  Row6 F1 = build_row(myH, giB, r0w + 1);
  Row6 F2 = build_row(myH, giB, r0w + 2);
  float mu0, mu1, mu2;
  {
    const float4* h0 = (const float4*)(myH + (r0w + 0) * 12);
    const float4* h1 = (const float4*)(myH + (r0w + 1) * 12);
    const float4* h2 = (const float4*)(myH + (r0w + 2) * 12);
    const float* y = auxB + 12;
    float u0 = dot12(h0[0], h0[1], h0[2], y);
    float u1 = dot12(h1[0], h1[1], h1[2], y);
    float u2 = dot12(h2[0], h2[1], h2[2], y);
    const float4* bv = (const float4*)bB;
    float d0 = 0.f, d1 = 0.f, d2 = 0.f;
    float4 v;
    v = bv[0]; FMA4(d0, F0.c0, v); FMA4(d1, F1.c0, v); FMA4(d2, F2.c0, v);
    v = bv[1]; FMA4(d0, F0.c1, v); FMA4(d1, F1.c1, v); FMA4(d2, F2.c1, v);
    v = bv[2]; FMA4(d0, F0.c2, v); FMA4(d1, F1.c2, v); FMA4(d2, F2.c2, v);
    v = bv[3]; FMA4(d0, F0.c3, v); FMA4(d1, F1.c3, v); FMA4(d2, F2.c3, v);
    v = bv[4]; FMA4(d0, F0.c4, v); FMA4(d1, F1.c4, v); FMA4(d2, F2.c4, v);
    v = bv[5]; FMA4(d0, F0.c5, v); FMA4(d1, F1.c5, v); FMA4(d2, F2.c5, v);
    mu0 = u0 - d0;
    mu1 = u1 - d1;
    mu2 = u2 - d2;
  }
  float cfr0 = cf[(size_t)env * 24 + r0w];
  float cfr1 = cf[(size_t)env * 24 + r0w + 1];
  float cfr2 = cf[(size_t)env * 24 + r0w + 2];

  // ---- iterations: wave-synchronous, ZERO barriers, single s buffer ----
  float l0 = 0.f, l1 = 0.f, l2 = 0.f, z0 = 0.f, z1 = 0.f, z2 = 0.f;
  float* sw = &sS[e * SS];
  for (int it = 0; it < niter; ++it) {
    float s0 = l0 + z0, s1 = l1 + z1, s2 = l2 + z2;
    sw[r0w] = s0; sw[r0w + 1] = s1; sw[r0w + 2] = s2;
    WFENCE();                         // compiler fence; DS in-order per wave
    const float4* sv = (const float4*)sw;
    float w0 = mu0, w1 = mu1, w2 = mu2;
    float4 c;
    c = sv[0]; FMA4(w0, F0.c0, c); FMA4(w1, F1.c0, c); FMA4(w2, F2.c0, c);
    c = sv[1]; FMA4(w0, F0.c1, c); FMA4(w1, F1.c1, c); FMA4(w2, F2.c1, c);
    c = sv[2]; FMA4(w0, F0.c2, c); FMA4(w1, F1.c2, c); FMA4(w2, F2.c2, c);
    c = sv[3]; FMA4(w0, F0.c3, c); FMA4(w1, F1.c3, c); FMA4(w2, F2.c3, c);
    c = sv[4]; FMA4(w0, F0.c4, c); FMA4(w1, F1.c4, c); FMA4(w2, F2.c4, c);
    c = sv[5]; FMA4(w0, F0.c5, c); FMA4(w1, F1.c5, c); FMA4(w2, F2.c5, c);
    WFENCE();                         // reads of this iter before next store
    float zp0 = fmaf(-2.0f, w0, s0);
    float zp1 = fmaf(-2.0f, w1, s1);
    float zp2 = fmaf(-2.0f, w2, s2);
    l0 = w0; l1 = w1; l2 = w2;
    if (t < 4) {
      float m = (zp2 > 0.0f) ? 1.0f : 0.0f;
      z0 = zp0 * m * cfr0; z1 = zp1 * m * cfr1; z2 = zp2 * m * cfr2;
    } else {
      z0 = fminf(fmaxf(zp0, -10.0f), 10.0f) * cfr0;
      z1 = fminf(fmaxf(zp1, -10.0f), 10.0f) * cfr1;
      z2 = fminf(fmaxf(zp2, -10.0f), 10.0f) * cfr2;
    }
  }

  // ---- outputs: lz, then x = (HtH)^-1 Ht (z - b) ----
  float* xout  = out;
  float* lzout = out + (size_t)Btot * 12;
  lzout[(size_t)env * 48 + r0w]          = l0;
  lzout[(size_t)env * 48 + r0w + 1]      = l1;
  lzout[(size_t)env * 48 + r0w + 2]      = l2;
  lzout[(size_t)env * 48 + 24 + r0w]     = z0;
  lzout[(size_t)env * 48 + 24 + r0w + 1] = z1;
  lzout[(size_t)env * 48 + 24 + r0w + 2] = z2;

  float bo0 = b[(size_t)env * 24 + r0w];
  float bo1 = b[(size_t)env * 24 + r0w + 1];
  float bo2 = b[(size_t)env * 24 + r0w + 2];
  WFENCE();
  auxB[r0w]     = z0 - bo0;
  auxB[r0w + 1] = z1 - bo1;
  auxB[r0w + 2] = z2 - bo2;
  WFENCE();

  float rv0 = 0.f, rv8 = 0.f;
#pragma unroll
  for (int k = 0; k < 24; ++k) rv0 = fmaf(myH[k * 12 + t], auxB[k], rv0);
  if (t < 4) {
#pragma unroll
    for (int k = 0; k < 24; ++k) rv8 = fmaf(myH[k * 12 + t + 8], auxB[k], rv8);
  }
  build_gram_row(myH, giB, t, false);
  if (t < 4) build_gram_row(myH, giB, t + 8, false);
  WFENCE();
  auxB[t] = rv0;
  if (t < 4) auxB[t + 8] = rv8;
  WFENCE();

  gj_all<0>(giB, t);
  {
    const float4* gr = (const float4*)(giB + t * 12);
    xout[(size_t)env * 12 + t] = dot12(gr[0], gr[1], gr[2], auxB);
    if (t < 4) {
      const float4* gr8 = (const float4*)(giB + (t + 8) * 12);
      xout[(size_t)env * 12 + t + 8] = dot12(gr8[0], gr8[1], gr8[2], auxB);
    }
  }
}

extern "C" void kernel_launch(void* const* d_in, const int* in_sizes, int n_in,
                              void* d_out, int out_size, void* d_ws, size_t ws_size,
                              hipStream_t stream) {
  const float* P  = (const float*)d_in[0];
  const float* q  = (const float*)d_in[1];
  const float* H  = (const float*)d_in[2];
  const float* b  = (const float*)d_in[3];
  const float* cf = (const float*)d_in[4];
  const int*   it = (const int*)d_in[5];
  float* out = (float*)d_out;
  const int B = in_sizes[1] / 12;       // q is [B,12]
  const int grid = B / EPB;             // 16384/8 = 2048 one-wave blocks
  pdhg_kernel<<<grid, BLOCK, 0, stream>>>(P, q, H, b, cf, it, out, B);
}